// Round 2
// baseline (70.592 us; speedup 1.0000x reference)
//
#include <hip/hip_runtime.h>

#define HEADN   2000
#define NSAMP   100
#define KC      10
#define CLIPV   20.0f
#define BATCH   2048
#define NCLASS  50000
#define TAILSCL 480.0f   // (50000-2000)/100

__device__ __forceinline__ float clipf(float x) {
    return fminf(fmaxf(x, -CLIPV), CLIPV);
}

// fast softplus(x) = log(1+exp(x)) via hardware v_exp_f32 / v_log_f32.
// x pre-clipped to [-20,20]: 1+exp(x) in [1, 4.9e8], no overflow; abs error
// at x=-20 is 2e-9 (irrelevant vs 803 absolute threshold).
__device__ __forceinline__ float sp(float x) {
    return __logf(1.0f + __expf(x));
}

__global__ __launch_bounds__(256) void fused_loss_kernel(
        const float* __restrict__ logits,
        const int*   __restrict__ cand,
        const int*   __restrict__ samp,
        float*       __restrict__ row_out,
        unsigned*    __restrict__ counter,
        float*       __restrict__ out)
{
    const int b   = blockIdx.x;
    const int tid = threadIdx.x;
    const float* lg = logits + (size_t)b * NCLASS;

    __shared__ int   s_cand[KC];
    __shared__ float s0[4], s1[4], s2[4];
    __shared__ int   s_last;

    if (tid < KC) s_cand[tid] = cand[b * KC + tid];
    __syncthreads();

    float candSum = 0.f;   // sum of clipped logits at distinct valid candidates
    float candCnt = 0.f;   // number of distinct valid candidates
    float acc     = 0.f;   // term2 partial + term3 partial

    // ---- Phase A: candidates (threads 0..KC-1), dedupe via LDS ----
    if (tid < KC) {
        const int ci = s_cand[tid];
        if (ci >= 0) {
            bool distinct = true;
            #pragma unroll
            for (int j = 0; j < KC; ++j)
                if (j < tid && s_cand[j] == ci) distinct = false;
            if (distinct) {
                float x = clipf(lg[ci]);
                candSum = x;
                candCnt = 1.f;
                if (ci < HEADN) acc -= sp(x);  // masked out of term2
            }
        }
    }

    // ---- Phase B: head softplus sum (unmasked; correction in phase A) ----
    const float4* lg4 = (const float4*)lg;
    #pragma unroll 2
    for (int i = tid; i < HEADN / 4; i += 256) {
        float4 v = lg4[i];
        acc += sp(clipf(v.x)) + sp(clipf(v.y)) + sp(clipf(v.z)) + sp(clipf(v.w));
    }

    // ---- Phase C: sampled tail (threads 0..NSAMP-1) ----
    if (tid < NSAMP) {
        const int col = HEADN + samp[tid];
        bool is_cand = false;
        #pragma unroll
        for (int j = 0; j < KC; ++j)
            if (s_cand[j] == col) is_cand = true;   // LDS broadcast reads
        if (!is_cand) acc += TAILSCL * sp(clipf(lg[col]));
    }

    // ---- Block reduction: 3 values across 4 waves ----
    #pragma unroll
    for (int off = 32; off > 0; off >>= 1) {
        candSum += __shfl_down(candSum, off);
        candCnt += __shfl_down(candCnt, off);
        acc     += __shfl_down(acc, off);
    }
    const int wid = tid >> 6;
    if ((tid & 63) == 0) { s0[wid] = candSum; s1[wid] = candCnt; s2[wid] = acc; }
    __syncthreads();

    if (tid == 0) {
        float cs = s0[0] + s0[1] + s0[2] + s0[3];
        float cc = s1[0] + s1[1] + s1[2] + s1[3];
        float a  = s2[0] + s2[1] + s2[2] + s2[3];
        float avg = cs / fmaxf(cc, 1.f);
        row_out[b] = sp(-avg) + a;        // psi(avg) + term2 + term3
        __threadfence();                  // release row_out before signaling
        unsigned prev = atomicAdd(counter, 1u);
        s_last = (prev == (unsigned)(BATCH - 1));
    }
    __syncthreads();

    // ---- Last block computes the mean (deterministic fixed-order sum) ----
    if (s_last) {
        __threadfence();                  // acquire all row_out writes
        float s = 0.f;
        #pragma unroll 8
        for (int i = tid; i < BATCH; i += 256) s += row_out[i];
        #pragma unroll
        for (int off = 32; off > 0; off >>= 1) s += __shfl_down(s, off);
        __syncthreads();                  // s0 reuse barrier
        if ((tid & 63) == 0) s0[tid >> 6] = s;
        __syncthreads();
        if (tid == 0) out[0] = (s0[0] + s0[1] + s0[2] + s0[3]) / (float)BATCH;
    }
}

extern "C" void kernel_launch(void* const* d_in, const int* in_sizes, int n_in,
                              void* d_out, int out_size, void* d_ws, size_t ws_size,
                              hipStream_t stream) {
    const float* logits = (const float*)d_in[0];
    const int*   cand   = (const int*)d_in[1];
    const int*   samp   = (const int*)d_in[2];
    float*    row_out = (float*)d_ws;                 // BATCH floats
    unsigned* counter = (unsigned*)((char*)d_ws + BATCH * sizeof(float));
    float*    out     = (float*)d_out;

    // d_ws is poisoned to 0xAA and never re-poisoned: zero the counter each
    // call (hipMemsetAsync on stream is graph-capturable).
    hipMemsetAsync(counter, 0, sizeof(unsigned), stream);
    fused_loss_kernel<<<BATCH, 256, 0, stream>>>(logits, cand, samp,
                                                 row_out, counter, out);
}

// Round 3
// 15.651 us; speedup vs baseline: 4.5105x; 4.5105x over previous
//
#include <hip/hip_runtime.h>

#define HEADN   2000
#define NSAMP   100
#define KC      10
#define CLIPV   20.0f
#define BATCH   2048
#define NCLASS  50000
#define TAILSCL 480.0f   // (50000-2000)/100

__device__ __forceinline__ float clipf(float x) {
    return fminf(fmaxf(x, -CLIPV), CLIPV);
}

// fast softplus(x) = log(1+exp(x)) via hardware v_exp_f32 / v_log_f32.
// x pre-clipped to [-20,20]: 1+exp(x) in [1, 4.9e8]; abs error <= 2e-9 at
// x=-20 (threshold is 803 absolute), rel error ~1e-7 elsewhere.
__device__ __forceinline__ float sp(float x) {
    return __logf(1.0f + __expf(x));
}

// One row per WAVE: 512 blocks x 4 waves, no __syncthreads, no LDS.
__global__ __launch_bounds__(256) void row_loss_wave(
        const float* __restrict__ logits,
        const int*   __restrict__ cand,
        const int*   __restrict__ samp,
        float*       __restrict__ row_out)
{
    const int tid  = threadIdx.x;
    const int lane = tid & 63;
    const int row  = blockIdx.x * 4 + (tid >> 6);
    const float* lg = logits + (size_t)row * NCLASS;

    // ---- candidates: lanes 0..9 load, broadcast to named regs (static idx) ----
    const int cl = (lane < KC) ? cand[row * KC + lane] : -1;
    const int c0 = __shfl(cl, 0), c1 = __shfl(cl, 1), c2 = __shfl(cl, 2),
              c3 = __shfl(cl, 3), c4 = __shfl(cl, 4), c5 = __shfl(cl, 5),
              c6 = __shfl(cl, 6), c7 = __shfl(cl, 7), c8 = __shfl(cl, 8),
              c9 = __shfl(cl, 9);

    float candSum = 0.f, candCnt = 0.f, acc = 0.f;

    // ---- Phase A: distinct valid candidates (dup collapses under .max) ----
    if (lane < KC && cl >= 0) {
        bool distinct = true;
        if (lane > 0 && c0 == cl) distinct = false;
        if (lane > 1 && c1 == cl) distinct = false;
        if (lane > 2 && c2 == cl) distinct = false;
        if (lane > 3 && c3 == cl) distinct = false;
        if (lane > 4 && c4 == cl) distinct = false;
        if (lane > 5 && c5 == cl) distinct = false;
        if (lane > 6 && c6 == cl) distinct = false;
        if (lane > 7 && c7 == cl) distinct = false;
        if (lane > 8 && c8 == cl) distinct = false;
        if (distinct) {
            float x = clipf(lg[cl]);
            candSum = x;
            candCnt = 1.f;
            if (cl < HEADN) acc -= sp(x);   // masked out of term2
        }
    }

    // ---- Phase B: head softplus sum, 500 float4 per row over 64 lanes ----
    const float4* lg4 = (const float4*)lg;
    #pragma unroll
    for (int k = 0; k < 7; ++k) {           // i = lane..lane+384, all < 500
        float4 v = lg4[lane + 64 * k];
        acc += sp(clipf(v.x)) + sp(clipf(v.y)) + sp(clipf(v.z)) + sp(clipf(v.w));
    }
    {
        int i = lane + 448;                 // tail: lanes 0..51
        if (i < HEADN / 4) {
            float4 v = lg4[i];
            acc += sp(clipf(v.x)) + sp(clipf(v.y)) + sp(clipf(v.z)) + sp(clipf(v.w));
        }
    }

    // ---- Phase C: 100 sampled tail cols, 2 rounds over 64 lanes ----
    {
        const int col = HEADN + samp[lane];             // lanes 0..63
        bool isc = (col == c0) | (col == c1) | (col == c2) | (col == c3) |
                   (col == c4) | (col == c5) | (col == c6) | (col == c7) |
                   (col == c8) | (col == c9);
        if (!isc) acc += TAILSCL * sp(clipf(lg[col]));
    }
    if (lane < NSAMP - 64) {                            // lanes 0..35
        const int col = HEADN + samp[lane + 64];
        bool isc = (col == c0) | (col == c1) | (col == c2) | (col == c3) |
                   (col == c4) | (col == c5) | (col == c6) | (col == c7) |
                   (col == c8) | (col == c9);
        if (!isc) acc += TAILSCL * sp(clipf(lg[col]));
    }

    // ---- 64-lane butterfly reduce (3 values) ----
    #pragma unroll
    for (int off = 32; off > 0; off >>= 1) {
        candSum += __shfl_xor(candSum, off);
        candCnt += __shfl_xor(candCnt, off);
        acc     += __shfl_xor(acc, off);
    }

    if (lane == 0) {
        float avg = candSum / fmaxf(candCnt, 1.f);
        row_out[row] = sp(-avg) + acc;      // psi(avg) + term2 + term3
    }
}

__global__ __launch_bounds__(256) void mean_kernel(
        const float* __restrict__ row, float* __restrict__ out)
{
    const int tid = threadIdx.x;
    const float4* r4 = (const float4*)row;
    float s = 0.f;
    #pragma unroll
    for (int k = 0; k < BATCH / 4 / 256; ++k) {     // 2 float4 per thread
        float4 v = r4[tid + 256 * k];
        s += v.x + v.y + v.z + v.w;
    }
    #pragma unroll
    for (int off = 32; off > 0; off >>= 1) s += __shfl_xor(s, off);
    __shared__ float sw[4];
    if ((tid & 63) == 0) sw[tid >> 6] = s;
    __syncthreads();
    if (tid == 0) out[0] = (sw[0] + sw[1] + sw[2] + sw[3]) / (float)BATCH;
}

extern "C" void kernel_launch(void* const* d_in, const int* in_sizes, int n_in,
                              void* d_out, int out_size, void* d_ws, size_t ws_size,
                              hipStream_t stream) {
    const float* logits = (const float*)d_in[0];
    const int*   cand   = (const int*)d_in[1];
    const int*   samp   = (const int*)d_in[2];
    float* row_out = (float*)d_ws;          // BATCH floats of scratch
    float* out     = (float*)d_out;

    row_loss_wave<<<BATCH / 4, 256, 0, stream>>>(logits, cand, samp, row_out);
    mean_kernel<<<1, 256, 0, stream>>>(row_out, out);
}